// Round 1
// 1075.389 us; speedup vs baseline: 1.3938x; 1.3938x over previous
//
#include <hip/hip_runtime.h>
#include <math.h>

// Problem constants
#define T_SEQ 300
#define E_DIM 300
#define H_DIM 512
#define G4    2048          // 4*H
#define NEXPT 13
#define NBLK  256           // persistent blocks, block b owns cells {2b, 2b+1}

__device__ __forceinline__ float sigm(float x) { return 1.0f / (1.0f + __expf(-x)); }
__device__ __forceinline__ float ftanh(float x) {
  x = fminf(15.0f, fmaxf(-15.0f, x));
  float u = __expf(2.0f * x);
  return (u - 1.0f) / (u + 1.0f);
}

// ---------------------------------------------------------------------------
// Fully fused routed LSTM. 256 blocks x 256 threads (cooperative), 1 block/CU.
// Block b owns cells {2b,2b+1} -> gate rows {q*512+2b+p}, q=0..3 (i,f,g,o).
//
// Fusion: the former pregates kernel is folded into the recurrent kernel's
// poll-idle time (VALUBusy was 4.2% -> plenty of slack):
//   - W_ih slice (8 rows x 300 x 13 experts = 124.8 KB) preloaded to LDS once.
//   - emb row for step t staged in a 2-deep LDS ring, prefetched 2 steps ahead
//     (HBM latency hides under the h-poll; same-parity overwrite is ordered by
//     barrier A: pre-gate reads happen pre-A, the refill write post-A).
//   - x-dot partials accumulate into the same 32-lane shuffle reduction as the
//     h-dot, so the pre-gate costs ~10 FMAs/thread/step and zero extra sync.
// This removes the pregates dispatch, the 2.4 MB pg buffer, and one launch.
//
// Poll fix: both u64 entries a thread waits on come from the SAME producer
// block, so they become valid together. Polling them sequentially (old code)
// paid one full dependent load latency per step; now both loads are issued
// before either is checked.
//
// Barrier C (loop end): lets the producer store issue before other waves dump
// next-step weight loads into the vmem queue. The weight loads have ~2 us of
// poll slack, so delaying them is free; the h-store is the grid-wide critical
// op and must not queue behind 16 loads.
// ---------------------------------------------------------------------------
__global__ void __launch_bounds__(256) lstm_fused_kernel(
    const int* __restrict__ x, const int* __restrict__ tags,
    const float* __restrict__ h0, const float* __restrict__ c0,
    const float* __restrict__ emb,
    const float* __restrict__ W_ih, const float* __restrict__ W_hh,
    const float* __restrict__ b_ih, const float* __restrict__ b_hh,
    const float* __restrict__ fc_w, const float* __restrict__ fc_b,
    unsigned long long* __restrict__ hbuf, float* __restrict__ out)
{
  const int b = blockIdx.x, tid = threadIdx.x;
  const int row_local = tid >> 5, lane_k = tid & 31;
  const int q = row_local >> 1, p = row_local & 1;
  const int rowG = q * H_DIM + 2 * b + p;

  __shared__ int tags_l[T_SEQ];
  __shared__ int x_l[T_SEQ];
  __shared__ __align__(16) float wihL[NEXPT][8][E_DIM];   // 124.8 KB
  __shared__ __align__(16) float ebuf[2][E_DIM];          // emb ring, parity t&1
  __shared__ float biasL[NEXPT][8];                       // b_ih + b_hh
  __shared__ __align__(16) float h_lds[2][H_DIM];
  __shared__ float gates_l[8];
  __shared__ float red[4];

  for (int i = tid; i < T_SEQ; i += 256) { tags_l[i] = tags[i]; x_l[i] = x[i]; }

  // W_ih LDS preload: this block's 8 gate rows, all 13 experts, float4.
  // 7800 = 13 * 8 * (300/4); rows are 1200 B apart -> 16 B aligned.
  for (int idx = tid; idx < 7800; idx += 256) {
    int e = idx / 600, rem = idx - e * 600;
    int r = rem / 75,  k4  = rem - r * 75;
    int rg = (r >> 1) * H_DIM + 2 * b + (r & 1);
    ((float4*)&wihL[e][r][0])[k4] =
        ((const float4*)(W_ih + ((size_t)e * G4 + rg) * E_DIM))[k4];
  }
  if (tid < NEXPT * 8) {
    int e = tid >> 3, r = tid & 7;
    int rg = (r >> 1) * H_DIM + 2 * b + (r & 1);
    biasL[e][r] = b_ih[e * G4 + rg] + b_hh[e * G4 + rg];
  }
  float c_r = 0.f, h_r = 0.f;
  if (tid < 2) c_r = c0[2 * b + tid];
  __syncthreads();

  // Warm the emb ring for t=0,1 (needs x_l, hence after the sync above).
  if (tid < E_DIM / 2) {
    ((float2*)ebuf[0])[tid] = ((const float2*)(emb + (size_t)x_l[0] * E_DIM))[tid];
    ((float2*)ebuf[1])[tid] = ((const float2*)(emb + (size_t)x_l[1] * E_DIM))[tid];
  }
  __syncthreads();

  for (int t = 0; t < T_SEQ; ++t) {
    const int e = tags_l[t];
    // Issue W_hh fragment + emb(t+2) loads BEFORE polling: addresses depend
    // only on tags/x, so L2/L3/HBM latency overlaps the spin-wait.
    const float4* wr = (const float4*)(W_hh + ((size_t)e * G4 + rowG) * H_DIM) + lane_k * 4;
    float4 w0 = wr[0], w1 = wr[1], w2 = wr[2], w3 = wr[3];
    float2 epf = make_float2(0.f, 0.f);
    if (t + 2 < T_SEQ && tid < E_DIM / 2)
      epf = ((const float2*)(emb + (size_t)x_l[t + 2] * E_DIM))[tid];

    // Pre-gate partial (pure LDS + VALU, hidden under the poll).
    // Lane covers k in [10*lane, 10*lane+10) of the 300-dot; lanes 30/31 idle.
    float acc = 0.f;
    {
      const float* wp = &wihL[e][row_local][0];
      const float* ep = &ebuf[t & 1][0];
      int k0 = lane_k * 10, kend = k0 + 10;
      if (kend > E_DIM) kend = E_DIM;
      for (int k = k0; k < kend; ++k) acc += wp[k] * ep[k];
    }

    float* hl = h_lds[t & 1];
    if (t == 0) {
      ((float2*)hl)[tid] = ((const float2*)h0)[tid];
    } else {
      unsigned long long* src = hbuf + (size_t)((t - 1) & 1) * H_DIM + 2 * tid;
      const unsigned tag = (unsigned)t;
      // Overlapped poll: both loads in flight before either check.
      unsigned long long v0 = __hip_atomic_load(src,     __ATOMIC_RELAXED, __HIP_MEMORY_SCOPE_AGENT);
      unsigned long long v1 = __hip_atomic_load(src + 1, __ATOMIC_RELAXED, __HIP_MEMORY_SCOPE_AGENT);
      while ((unsigned)v0 != tag || (unsigned)v1 != tag) {
        if ((unsigned)v0 != tag) v0 = __hip_atomic_load(src,     __ATOMIC_RELAXED, __HIP_MEMORY_SCOPE_AGENT);
        if ((unsigned)v1 != tag) v1 = __hip_atomic_load(src + 1, __ATOMIC_RELAXED, __HIP_MEMORY_SCOPE_AGENT);
      }
      hl[2 * tid]     = __uint_as_float((unsigned)(v0 >> 32));
      hl[2 * tid + 1] = __uint_as_float((unsigned)(v1 >> 32));
    }
    __syncthreads();   // barrier A: h staged; all ebuf[t&1] pre-gate reads done

    const float4* hv = (const float4*)hl + lane_k * 4;
    float4 a0 = hv[0], a1 = hv[1], a2 = hv[2], a3 = hv[3];
    acc += w0.x*a0.x + w0.y*a0.y + w0.z*a0.z + w0.w*a0.w
         + w1.x*a1.x + w1.y*a1.y + w1.z*a1.z + w1.w*a1.w
         + w2.x*a2.x + w2.y*a2.y + w2.z*a2.z + w2.w*a2.w
         + w3.x*a3.x + w3.y*a3.y + w3.z*a3.z + w3.w*a3.w;
    // Refill the emb ring for t+2 (same parity as t; safe post-A).
    if (t + 2 < T_SEQ && tid < E_DIM / 2) ((float2*)ebuf[t & 1])[tid] = epf;
    #pragma unroll
    for (int m = 16; m >= 1; m >>= 1) acc += __shfl_xor(acc, m, 32);
    if (lane_k == 0) gates_l[row_local] = acc + biasL[e][row_local];
    __syncthreads();   // barrier B: gates ready

    if (tid < 2) {
      float iv = sigm(gates_l[0 + tid]);
      float fv = sigm(gates_l[2 + tid]);
      float gv = ftanh(gates_l[4 + tid]);
      float ov = sigm(gates_l[6 + tid]);
      c_r = fv * c_r + iv * gv;
      h_r = ov * ftanh(c_r);
      unsigned long long pv =
          ((unsigned long long)__float_as_uint(h_r) << 32) | (unsigned)(t + 1);
      __hip_atomic_store(hbuf + (size_t)(t & 1) * H_DIM + 2 * b + tid, pv,
                         __ATOMIC_RELAXED, __HIP_MEMORY_SCOPE_AGENT);
    }
    __syncthreads();   // barrier C: h-store issues before next-step load burst
  }

  if (tid < 2) {
    out[1   + 2 * b + tid] = h_r;   // h slice
    out[513 + 2 * b + tid] = c_r;   // c slice
  }

  if (b == 0) {  // final scalar: sigmoid(h . fc_w + fc_b)
    unsigned long long* src = hbuf + (size_t)((T_SEQ - 1) & 1) * H_DIM + 2 * tid;
    unsigned long long v0, v1;
    do { v0 = __hip_atomic_load(src,     __ATOMIC_RELAXED, __HIP_MEMORY_SCOPE_AGENT); } while ((unsigned)v0 != (unsigned)T_SEQ);
    do { v1 = __hip_atomic_load(src + 1, __ATOMIC_RELAXED, __HIP_MEMORY_SCOPE_AGENT); } while ((unsigned)v1 != (unsigned)T_SEQ);
    float hv0 = __uint_as_float((unsigned)(v0 >> 32));
    float hv1 = __uint_as_float((unsigned)(v1 >> 32));
    float a = hv0 * fc_w[2 * tid] + hv1 * fc_w[2 * tid + 1];
    #pragma unroll
    for (int m = 32; m >= 1; m >>= 1) a += __shfl_xor(a, m, 64);
    if ((tid & 63) == 0) red[tid >> 6] = a;
    __syncthreads();
    if (tid == 0) out[0] = sigm(red[0] + red[1] + red[2] + red[3] + fc_b[0]);
  }
}

// ---------------------------------------------------------------------------
extern "C" void kernel_launch(void* const* d_in, const int* in_sizes, int n_in,
                              void* d_out, int out_size, void* d_ws, size_t ws_size,
                              hipStream_t stream) {
  const int*   x    = (const int*)d_in[0];
  const int*   tags = (const int*)d_in[1];
  const float* h0   = (const float*)d_in[2];
  const float* c0   = (const float*)d_in[3];
  const float* emb  = (const float*)d_in[4];
  const float* W_ih = (const float*)d_in[5];
  const float* W_hh = (const float*)d_in[6];
  const float* b_ih = (const float*)d_in[7];
  const float* b_hh = (const float*)d_in[8];
  const float* fc_w = (const float*)d_in[9];
  const float* fc_b = (const float*)d_in[10];
  float* out = (float*)d_out;

  // Workspace: only the h exchange buffer (2*512 u64 = 8 KB) remains.
  // Poisoned 0xAA each launch == invalid tag, by design.
  unsigned long long* hbuf = (unsigned long long*)d_ws;

  void* args[] = { (void*)&x, (void*)&tags, (void*)&h0, (void*)&c0,
                   (void*)&emb, (void*)&W_ih, (void*)&W_hh, (void*)&b_ih,
                   (void*)&b_hh, (void*)&fc_w, (void*)&fc_b, (void*)&hbuf,
                   (void*)&out };
  hipLaunchCooperativeKernel((const void*)lstm_fused_kernel, dim3(NBLK),
                             dim3(256), args, 0, stream);
}